// Round 8
// baseline (3324.265 us; speedup 1.0000x reference)
//
#include <hip/hip_runtime.h>
#include <math.h>

// Problem constants: B=16384 samples, DIM=64, WIDTH=256, DD=64, C2=16
#define SB 16      // samples per workgroup
#define PAD 17     // LDS row pad for transposed [neuron][sample] tiles (k1)

// ws layout (float offsets)
#define OFF_W0T  0            // 5 x (64x256)
#define OFF_W1T  81920        // 5 x (256x256)
#define OFF_W2PT 409600       // 256x2016
#define OFF_W2CT 925696       // 256x1024
#define OFF_W2BT 1187840      // 256x4096
#define OFF_DE   2236416      // 16384x64
#define OFF_DS   3284992      // 16384x64
#define WS_FLOATS 4337600     // ~17.35 MB

__device__ __forceinline__ void fma16(float* acc0, float* acc1, float a0, float a1,
                                      float4 wA, float4 wB) {
    float w[8] = {wA.x, wA.y, wA.z, wA.w, wB.x, wB.y, wB.z, wB.w};
    #pragma unroll
    for (int q = 0; q < 8; ++q) {
        acc0[q] = fmaf(a0, w[q], acc0[q]);
        acc1[q] = fmaf(a1, w[q], acc1[q]);
    }
}

__device__ __forceinline__ float4 f4fma(float a, float4 w, float4 c) {
    c.x = fmaf(a, w.x, c.x); c.y = fmaf(a, w.y, c.y);
    c.z = fmaf(a, w.z, c.z); c.w = fmaf(a, w.w, c.w);
    return c;
}

__device__ __forceinline__ float dot4f(float4 a, float4 b) {
    return fmaf(a.w, b.w, fmaf(a.z, b.z, fmaf(a.y, b.y, a.x * b.x)));
}

__device__ __forceinline__ float4 tanh4b(float4 a, float b) {
    return make_float4(tanhf(a.x + b), tanhf(a.y + b), tanhf(a.z + b), tanhf(a.w + b));
}

// out[c*R + r] = in[r*C + c]   (in: R rows x C cols, row-major)
__global__ void k_transpose(const float* __restrict__ in, float* __restrict__ out, int R, int C) {
    int tid = blockIdx.x * blockDim.x + threadIdx.x;
    if (tid >= R * C) return;
    int c = tid / R, r = tid - c * R;
    out[tid] = in[r * C + c];
}

// ---------------- K1: dE, dS (energy/entropy forward + analytic backward) ----------------
__global__ __launch_bounds__(256) void k1_grads(
    const float* __restrict__ y, const float* __restrict__ ws,
    const float* __restrict__ W0E, const float* __restrict__ b0E,
    const float* __restrict__ W1E, const float* __restrict__ b1E,
    const float* __restrict__ w2E,
    const float* __restrict__ W0S, const float* __restrict__ b0S,
    const float* __restrict__ W1S, const float* __restrict__ b1S,
    const float* __restrict__ w2S,
    float* __restrict__ odE, float* __restrict__ odS)
{
    __shared__ float sYT[64][PAD];
    __shared__ float sH1T[256][PAD];
    __shared__ float sH2T[256][PAD];
    __shared__ float sUT[256][PAD];

    const int tid = threadIdx.x;
    const int sbase = blockIdx.x * SB;
    for (int idx = tid; idx < SB * 64; idx += 256) {
        int s = idx >> 6, i = idx & 63;
        sYT[i][s] = y[(sbase + s) * 64 + i];
    }
    __syncthreads();

    const int ts = tid >> 5, tn = tid & 31;
    const int s0 = 2 * ts, s1 = s0 + 1;

    for (int m = 0; m < 2; ++m) {
        const float* w0t = ws + OFF_W0T + m * 16384;
        const float* w1t = ws + OFF_W1T + m * 65536;
        const float* W0 = m ? W0S : W0E;
        const float* W1 = m ? W1S : W1E;
        const float* b0 = m ? b0S : b0E;
        const float* b1 = m ? b1S : b1E;
        const float* w2 = m ? w2S : w2E;
        float* outg = m ? odS : odE;

        // H1 = tanh(Y @ W0^T + b0), K=64
        {
            float acc0[8] = {0}, acc1[8] = {0};
            #pragma unroll 4
            for (int k = 0; k < 64; ++k) {
                float a0 = sYT[k][s0], a1 = sYT[k][s1];
                float4 wA = *(const float4*)(w0t + k * 256 + tn * 8);
                float4 wB = *(const float4*)(w0t + k * 256 + tn * 8 + 4);
                fma16(acc0, acc1, a0, a1, wA, wB);
            }
            #pragma unroll
            for (int q = 0; q < 8; ++q) {
                int j = tn * 8 + q;
                float b = b0[j];
                sH1T[j][s0] = tanhf(acc0[q] + b);
                sH1T[j][s1] = tanhf(acc1[q] + b);
            }
        }
        __syncthreads();
        // H2 = tanh(H1 @ W1^T + b1), K=256
        {
            float acc0[8] = {0}, acc1[8] = {0};
            #pragma unroll 4
            for (int k = 0; k < 256; ++k) {
                float a0 = sH1T[k][s0], a1 = sH1T[k][s1];
                float4 wA = *(const float4*)(w1t + k * 256 + tn * 8);
                float4 wB = *(const float4*)(w1t + k * 256 + tn * 8 + 4);
                fma16(acc0, acc1, a0, a1, wA, wB);
            }
            #pragma unroll
            for (int q = 0; q < 8; ++q) {
                int j = tn * 8 + q;
                float b = b1[j];
                sH2T[j][s0] = tanhf(acc0[q] + b);
                sH2T[j][s1] = tanhf(acc1[q] + b);
            }
        }
        __syncthreads();
        // G2 = (1 - H2^2) * w2  (in place)
        for (int idx = tid; idx < 256 * SB; idx += 256) {
            int j = idx >> 4, s = idx & 15;
            float h = sH2T[j][s];
            sH2T[j][s] = (1.f - h * h) * w2[j];
        }
        __syncthreads();
        // U = G2 @ W1 (natural layout), fused G1 = (1-H1^2)*U
        {
            float acc0[8] = {0}, acc1[8] = {0};
            #pragma unroll 4
            for (int k = 0; k < 256; ++k) {
                float a0 = sH2T[k][s0], a1 = sH2T[k][s1];
                float4 wA = *(const float4*)(W1 + k * 256 + tn * 8);
                float4 wB = *(const float4*)(W1 + k * 256 + tn * 8 + 4);
                fma16(acc0, acc1, a0, a1, wA, wB);
            }
            #pragma unroll
            for (int q = 0; q < 8; ++q) {
                int ko = tn * 8 + q;
                float h0 = sH1T[ko][s0], h1v = sH1T[ko][s1];
                sUT[ko][s0] = (1.f - h0 * h0) * acc0[q];
                sUT[ko][s1] = (1.f - h1v * h1v) * acc1[q];
            }
        }
        __syncthreads();
        // dE = G1 @ W0 (natural layout)
        {
            float a00 = 0, a01 = 0, a10 = 0, a11 = 0;
            #pragma unroll 4
            for (int k = 0; k < 256; ++k) {
                float g0 = sUT[k][s0], g1 = sUT[k][s1];
                float2 w = *(const float2*)(W0 + k * 64 + tn * 2);
                a00 = fmaf(g0, w.x, a00); a01 = fmaf(g0, w.y, a01);
                a10 = fmaf(g1, w.x, a10); a11 = fmaf(g1, w.y, a11);
            }
            outg[(sbase + s0) * 64 + tn * 2]     = a00;
            outg[(sbase + s0) * 64 + tn * 2 + 1] = a01;
            outg[(sbase + s1) * 64 + tn * 2]     = a10;
            outg[(sbase + s1) * 64 + tn * 2 + 1] = a11;
        }
        __syncthreads();
    }
}

// ---------------- K2: pA head + poisson (atomic-free, weight-dedup), writes d_out ----------------
__global__ __launch_bounds__(1024, 4) void k2_poisson(
    const float* __restrict__ y, const float* __restrict__ ws,
    const float* __restrict__ b0P, const float* __restrict__ b1P,
    float* __restrict__ dout)
{
    extern __shared__ float smem[];
    float* sa   = smem;            // 16 x 2024 (a-values). Aliased: H1T @ [0,4096), yT @ [4096,5120)
    float* sH2T = smem + 32384;    // [256][16]
    float* sdE  = sH2T + 4096;     // [s][i]
    float* sdS  = sdE + 1024;
    // total 38528 floats = 154112 B

    float* sH1T = sa;              // alias [256][16] (dead before a-GEMM writes)
    float* syT  = sa + 4096;       // alias [64][16]  (dead after H1)

    const int tid = threadIdx.x;
    const int sbase = blockIdx.x * SB;
    const float* gdE = ws + OFF_DE;
    const float* gdS = ws + OFF_DS;

    // P0: one element per thread; y stored transposed
    {
        int s = tid >> 6, i = tid & 63;
        syT[i * 16 + s] = y[sbase * 64 + tid];
        sdE[tid] = gdE[sbase * 64 + tid];
        sdS[tid] = gdS[sbase * 64 + tid];
    }
    __syncthreads();

    const int c  = tid & 255;
    const int sg = tid >> 8;
    const int s4 = sg * 4;

    // P1: H1 = tanh(y @ W0^T + b0)
    {
        const float* w0t = ws + OFF_W0T + 2 * 16384;
        float4 acc = {0, 0, 0, 0};
        #pragma unroll 4
        for (int k = 0; k < 64; ++k) {
            float w = w0t[k * 256 + c];
            float4 yv = *(const float4*)(syT + k * 16 + s4);
            acc = f4fma(w, yv, acc);
        }
        *(float4*)(sH1T + c * 16 + s4) = tanh4b(acc, b0P[c]);
    }
    __syncthreads();

    // P2: H2 = tanh(H1 @ W1^T + b1)
    {
        const float* w1t = ws + OFF_W1T + 2 * 65536;
        float4 acc = {0, 0, 0, 0};
        #pragma unroll 4
        for (int k = 0; k < 256; ++k) {
            float w = w1t[k * 256 + c];
            float4 hv = *(const float4*)(sH1T + k * 16 + s4);
            acc = f4fma(w, hv, acc);
        }
        *(float4*)(sH2T + c * 16 + s4) = tanh4b(acc, b1P[c]);
    }
    __syncthreads();   // H1T/yT regions dead; sa fully writable

    // P3: a-GEMM, tiled 4 cols x 8 samples. cq<504 covers all 2016 cols.
    {
        const int sg2 = tid >> 9;           // 0..1 (sample octet)
        const int s8  = sg2 * 8;
        const int cq  = tid & 511;          // col quad
        if (cq < 504) {
            const float* wp = ws + OFF_W2PT + 4 * cq;
            float4 acc[8];
            #pragma unroll
            for (int s = 0; s < 8; ++s) acc[s] = make_float4(0.f, 0.f, 0.f, 0.f);
            #pragma unroll 2
            for (int k = 0; k < 256; ++k) {
                float4 hA = *(const float4*)(sH2T + k * 16 + s8);
                float4 hB = *(const float4*)(sH2T + k * 16 + s8 + 4);
                float4 w = *(const float4*)(wp + k * 2016);
                acc[0] = f4fma(hA.x, w, acc[0]);
                acc[1] = f4fma(hA.y, w, acc[1]);
                acc[2] = f4fma(hA.z, w, acc[2]);
                acc[3] = f4fma(hA.w, w, acc[3]);
                acc[4] = f4fma(hB.x, w, acc[4]);
                acc[5] = f4fma(hB.y, w, acc[5]);
                acc[6] = f4fma(hB.z, w, acc[6]);
                acc[7] = f4fma(hB.w, w, acc[7]);
            }
            #pragma unroll
            for (int s = 0; s < 8; ++s)
                *(float4*)(sa + (s8 + s) * 2024 + 4 * cq) = acc[s];
        }
    }
    __syncthreads();

    // P4: gather. thread -> sample s = tid>>6, row i = tid&63 (one wave per sample).
    {
        const int s = tid >> 6;
        const int i = tid & 63;
        const int ib = i * (i - 1) / 2;
        const float* ap = sa + s * 2024;
        const float* dep = sdE + s * 64;
        const float* dsp = sdS + s * 64;

        float adE = 0.f, adS = 0.f;
        int trij = 0;   // j*(j-1)/2
        #pragma unroll 4
        for (int j = 0; j < 64; ++j) {
            int t = (j < i) ? (ib + j) : (trij + i);
            float sel = (j < i) ? 1.f : ((j == i) ? 0.f : -1.f);
            float cc = sel * ap[t];
            adE = fmaf(cc, dep[j], adE);
            adS = fmaf(cc, dsp[j], adS);
            trij += j;
        }

        float de = dep[i], dsv = dsp[i];
        float p0 = de * adS;     // dE . AdS
        float p1 = de * dsv;     // dE . dS
        float p2 = dsv * dsv;    // dS . dS
        #pragma unroll
        for (int m = 1; m <= 32; m <<= 1) {
            p0 += __shfl_xor(p0, m);
            p1 += __shfl_xor(p1, m);
            p2 += __shfl_xor(p2, m);
        }
        float inv = 1.f / p2;
        dout[sbase * 64 + tid] = adE + (p0 * dsv - p1 * adS) * inv;
    }
}

// ---------------- K3: fC/fB heads + friction, accumulates into d_out ----------------
// 1024 threads, SB=16. SAMPLE-PER-LANE design: s = tid&15 in every GEMM phase,
// each thread owns a CONTIGUOUS col range = full output row(s):
//   forwards: (net, 8 cols, 1 sample); C: (C2-row of 16 cols, 1 sample);
//   Bm: (Bm row k'=tid>>4, 64 cols, 1 sample) -> bm[16] float4, i-reduction in-thread.
// h operand = 1 ds_read_b32 broadcast per k. Wave col-ranges disjoint -> every
// weight byte read once per block (5.6 MB vs 10.5). No shfl reductions needed.
__global__ __launch_bounds__(1024, 4) void k3_friction(
    const float* __restrict__ y, const float* __restrict__ ws,
    const float* __restrict__ b0C, const float* __restrict__ b1C,
    const float* __restrict__ b0B, const float* __restrict__ b1B,
    float* __restrict__ dout)
{
    extern __shared__ float smem[];
    float* sYT  = smem;               // [64][16]  y transposed
    float* sBTc = smem + 1024;        // [256][16] fC H2
    float* sBTb = smem + 5120;        // [256][16] fB H2
    float* sATc = smem + 9216;        // [256][16] fC H1 (dead after L1)
    float* sATb = smem + 13312;       // [256][16] fB H1 (dead after L1)
    float* sC   = smem + 9216;        // [16][1089] OVERLAPS sATc/sATb (written in C-head)
    float* sdE  = smem + 26640;       // [s][i]
    float* sdS  = sdE + 1024;
    float* sBdE = sdS + 1024;
    float* sBdS = sBdE + 1024;
    float* sv   = sBdS + 1024;
    float* sq   = sv + 1024;
    float* sScal = sq + 1024;         // 16*4
    float* sr   = sScal + 64;         // 16*16
    // total = 33104 floats = 132416 B

    const int tid = threadIdx.x;
    const int sbase = blockIdx.x * SB;
    const float* gdE = ws + OFF_DE;
    const float* gdS = ws + OFF_DS;

    {
        int s = tid >> 6, i = tid & 63;
        sYT[i * 16 + s] = y[sbase * 64 + tid];
        sdE[tid] = gdE[sbase * 64 + tid];
        sdS[tid] = gdS[sbase * 64 + tid];
    }
    if (tid < 64) sScal[tid] = 0.f;
    __syncthreads();

    {
        int s = tid >> 6;
        float de = sdE[tid];
        unsafeAtomicAdd(&sScal[s * 4 + 0], de * de);
        unsafeAtomicAdd(&sScal[s * 4 + 1], de * sdS[tid]);
    }

    const int sl = tid & 15;          // sample (lane-resident)
    const int p  = tid >> 4;          // 0..63: col-range owner

    // ---- forward mapping: net x col-octet x sample ----
    const int net = tid >> 9;         // 0=fC, 1=fB
    const int t9  = tid & 511;
    const int sf  = t9 & 15;          // sample
    const int g   = t9 >> 4;          // 0..31, cols [8g, 8g+8)
    const float* w0t = ws + OFF_W0T + (3 + net) * 16384;
    const float* w1t = ws + OFF_W1T + (3 + net) * 65536;
    const float* b0v = net ? b0B : b0C;
    const float* b1v = net ? b1B : b1C;
    float* sH1 = net ? sATb : sATc;
    float* sH2 = net ? sBTb : sBTc;

    // ============ L0 (both nets): H1 = tanh(y @ W0^T + b0), 8 cols x 1 sample ============
    {
        float4 a0 = {0,0,0,0}, a1 = {0,0,0,0};
        #pragma unroll 4
        for (int k = 0; k < 64; ++k) {
            float h = sYT[k * 16 + sf];
            float4 wA = *(const float4*)(w0t + k * 256 + 8 * g);
            float4 wB = *(const float4*)(w0t + k * 256 + 8 * g + 4);
            a0 = f4fma(h, wA, a0);
            a1 = f4fma(h, wB, a1);
        }
        float r0[8] = {a0.x, a0.y, a0.z, a0.w, a1.x, a1.y, a1.z, a1.w};
        #pragma unroll
        for (int j = 0; j < 8; ++j)
            sH1[(8 * g + j) * 16 + sf] = tanhf(r0[j] + b0v[8 * g + j]);
    }
    __syncthreads();

    // ============ L1 (both nets): H2 = tanh(H1 @ W1^T + b1) ============
    {
        float4 a0 = {0,0,0,0}, a1 = {0,0,0,0};
        #pragma unroll 4
        for (int k = 0; k < 256; ++k) {
            float h = sH1[k * 16 + sf];
            float4 wA = *(const float4*)(w1t + k * 256 + 8 * g);
            float4 wB = *(const float4*)(w1t + k * 256 + 8 * g + 4);
            a0 = f4fma(h, wA, a0);
            a1 = f4fma(h, wB, a1);
        }
        float r0[8] = {a0.x, a0.y, a0.z, a0.w, a1.x, a1.y, a1.z, a1.w};
        #pragma unroll
        for (int j = 0; j < 8; ++j)
            sH2[(8 * g + j) * 16 + sf] = tanhf(r0[j] + b1v[8 * g + j]);
    }
    __syncthreads();   // H1 tiles dead from here; sC region writable

    // ============ C head: thread = (sample sl, C2-row p), cols [16p,16p+16) ============
    {
        const float* wc = ws + OFF_W2CT + 16 * p;
        float4 ca[4];
        #pragma unroll
        for (int j = 0; j < 4; ++j) ca[j] = make_float4(0.f, 0.f, 0.f, 0.f);
        #pragma unroll 2
        for (int k = 0; k < 256; ++k) {
            float h = sBTc[k * 16 + sl];
            const float* wk = wc + k * 1024;
            ca[0] = f4fma(h, *(const float4*)(wk), ca[0]);
            ca[1] = f4fma(h, *(const float4*)(wk + 4), ca[1]);
            ca[2] = f4fma(h, *(const float4*)(wk + 8), ca[2]);
            ca[3] = f4fma(h, *(const float4*)(wk + 12), ca[3]);
        }
        float* dst = sC + sl * 1089 + p * 17;
        float cr[16] = {ca[0].x, ca[0].y, ca[0].z, ca[0].w,
                        ca[1].x, ca[1].y, ca[1].z, ca[1].w,
                        ca[2].x, ca[2].y, ca[2].z, ca[2].w,
                        ca[3].x, ca[3].y, ca[3].z, ca[3].w};
        #pragma unroll
        for (int m = 0; m < 16; ++m) dst[m] = cr[m];
    }
    __syncthreads();

    // ============ Bm pass1: thread = (sample sl, Bm-row p), cols [64p, 64p+64) ============
    float4 bm[16];
    #pragma unroll
    for (int j = 0; j < 16; ++j) bm[j] = make_float4(0.f, 0.f, 0.f, 0.f);
    {
        const float* wb = ws + OFF_W2BT + 64 * p;
        #pragma unroll 2
        for (int k = 0; k < 256; ++k) {
            float h = sBTb[k * 16 + sl];
            const float* wk = wb + k * 4096;
            #pragma unroll
            for (int j = 0; j < 16; ++j)
                bm[j] = f4fma(h, *(const float4*)(wk + 4 * j), bm[j]);
        }
    }
    // BdotdE/BdotdS: full i-reduction in-thread (no shfl)
    {
        float pd = 0.f, ps = 0.f;
        #pragma unroll
        for (int j = 0; j < 16; ++j) {
            float4 de = *(const float4*)(sdE + sl * 64 + 4 * j);
            float4 dsv = *(const float4*)(sdS + sl * 64 + 4 * j);
            pd += dot4f(bm[j], de);
            ps += dot4f(bm[j], dsv);
        }
        sBdE[sl * 64 + p] = pd;
        sBdS[sl * 64 + p] = ps;
    }
    __syncthreads();

    // v = BdS - beta*BdE  (one element per thread)
    {
        int s = tid >> 6;
        float beta = sScal[s * 4 + 1] / sScal[s * 4 + 0];
        sv[tid] = sBdS[tid] - beta * sBdE[tid];
    }
    __syncthreads();
    {
        int s = tid >> 6;
        unsafeAtomicAdd(&sScal[s * 4 + 2], sdE[tid] * sv[tid]);
    }
    __syncthreads();

    // ============ pass2: q = Bm @ v from registers ============
    {
        float pq = 0.f;
        #pragma unroll
        for (int j = 0; j < 16; ++j) {
            float4 vv = *(const float4*)(sv + sl * 64 + 4 * j);
            pq += dot4f(bm[j], vv);
        }
        sq[sl * 64 + p] = pq;
    }
    __syncthreads();

    // r[m] = sum_k C[k,m] * (q[k] - gamma*BdE[k])
    if (tid < 256) {
        int s = tid >> 4, m = tid & 15;
        float gamma = sScal[s * 4 + 2] / sScal[s * 4 + 0];
        float r = 0.f;
        #pragma unroll 4
        for (int k = 0; k < 64; ++k) {
            float wv = sq[s * 64 + k] - gamma * sBdE[s * 64 + k];
            r = fmaf(sC[s * 1089 + k * 17 + m], wv, r);
        }
        sr[s * 16 + m] = r;
    }
    __syncthreads();
    // out_k += sum_m C[k,m] * r[m]  (one element per thread)
    {
        int s = tid >> 6, k = tid & 63;
        float o = 0.f;
        #pragma unroll
        for (int m2 = 0; m2 < 16; ++m2)
            o = fmaf(sC[s * 1089 + k * 17 + m2], sr[s * 16 + m2], o);
        int gi = sbase * 64 + tid;
        dout[gi] = dout[gi] + o;
    }
}

extern "C" void kernel_launch(void* const* d_in, const int* in_sizes, int n_in,
                              void* d_out, int out_size, void* d_ws, size_t ws_size,
                              hipStream_t stream)
{
    (void)in_sizes; (void)n_in; (void)out_size;
    const float* y = (const float*)d_in[1];
    const float* W0[5]; const float* b0[5]; const float* W1[5]; const float* b1[5]; const float* W2[5];
    for (int m = 0; m < 5; ++m) {
        int base = 2 + m * 5;
        W0[m] = (const float*)d_in[base + 0];
        b0[m] = (const float*)d_in[base + 1];
        W1[m] = (const float*)d_in[base + 2];
        b1[m] = (const float*)d_in[base + 3];
        W2[m] = (const float*)d_in[base + 4];
    }
    float* ws = (float*)d_ws;
    float* dout = (float*)d_out;
    if (ws_size < (size_t)WS_FLOATS * sizeof(float)) return;

    for (int m = 0; m < 5; ++m) {
        hipLaunchKernelGGL(k_transpose, dim3((256 * 64 + 255) / 256), dim3(256), 0, stream,
                           W0[m], ws + OFF_W0T + m * 16384, 256, 64);
        hipLaunchKernelGGL(k_transpose, dim3((256 * 256 + 255) / 256), dim3(256), 0, stream,
                           W1[m], ws + OFF_W1T + m * 65536, 256, 256);
    }
    hipLaunchKernelGGL(k_transpose, dim3((2016 * 256 + 255) / 256), dim3(256), 0, stream,
                       W2[2], ws + OFF_W2PT, 2016, 256);
    hipLaunchKernelGGL(k_transpose, dim3((1024 * 256 + 255) / 256), dim3(256), 0, stream,
                       W2[3], ws + OFF_W2CT, 1024, 256);
    hipLaunchKernelGGL(k_transpose, dim3((4096 * 256 + 255) / 256), dim3(256), 0, stream,
                       W2[4], ws + OFF_W2BT, 4096, 256);

    hipLaunchKernelGGL(k1_grads, dim3(1024), dim3(256), 0, stream,
                       y, ws,
                       W0[0], b0[0], W1[0], b1[0], W2[0],
                       W0[1], b0[1], W1[1], b1[1], W2[1],
                       ws + OFF_DE, ws + OFF_DS);

    const int k2_smem = 154112;
    hipFuncSetAttribute((const void*)k2_poisson, hipFuncAttributeMaxDynamicSharedMemorySize, k2_smem);
    hipLaunchKernelGGL(k2_poisson, dim3(1024), dim3(1024), k2_smem, stream,
                       y, ws, b0[2], b1[2], dout);

    const int k3_smem = 132416;
    hipFuncSetAttribute((const void*)k3_friction, hipFuncAttributeMaxDynamicSharedMemorySize, k3_smem);
    hipLaunchKernelGGL(k3_friction, dim3(1024), dim3(1024), k3_smem, stream,
                       y, ws, b0[3], b1[3], b0[4], b1[4], dout);
}

// Round 9
// 1354.970 us; speedup vs baseline: 2.4534x; 2.4534x over previous
//
#include <hip/hip_runtime.h>
#include <math.h>

// Problem constants: B=16384 samples, DIM=64, WIDTH=256, DD=64, C2=16
#define SB 16      // samples per workgroup

// ws layout (float offsets)
#define OFF_W0T  0            // 5 x (64x256)
#define OFF_W1T  81920        // 5 x (256x256)
#define OFF_W2PT 409600       // 256x2016
#define OFF_W2CT 925696       // 256x1024
#define OFF_W2BT 1187840      // 256x4096
#define OFF_DE   2236416      // 16384x64
#define OFF_DS   3284992      // 16384x64
#define WS_FLOATS 4337600     // ~17.35 MB

__device__ __forceinline__ float4 f4fma(float a, float4 w, float4 c) {
    c.x = fmaf(a, w.x, c.x); c.y = fmaf(a, w.y, c.y);
    c.z = fmaf(a, w.z, c.z); c.w = fmaf(a, w.w, c.w);
    return c;
}

__device__ __forceinline__ float dot4f(float4 a, float4 b) {
    return fmaf(a.w, b.w, fmaf(a.z, b.z, fmaf(a.y, b.y, a.x * b.x)));
}

__device__ __forceinline__ float4 tanh4b(float4 a, float b) {
    return make_float4(tanhf(a.x + b), tanhf(a.y + b), tanhf(a.z + b), tanhf(a.w + b));
}

// out[c*R + r] = in[r*C + c]   (in: R rows x C cols, row-major)
__global__ void k_transpose(const float* __restrict__ in, float* __restrict__ out, int R, int C) {
    int tid = blockIdx.x * blockDim.x + threadIdx.x;
    if (tid >= R * C) return;
    int c = tid / R, r = tid - c * R;
    out[tid] = in[r * C + c];
}

// ---------------- K1: dE, dS (energy/entropy forward + analytic backward) ----------------
// 1024 threads, SB=16, 53 KB static LDS -> 2 blocks/CU (8 waves/SIMD).
// Forwards + U-pass: column c x sample-quad sg, transposed [neuron][16] tiles.
// dE-pass: thread (s=tid>>6 wave-uniform, i=tid&63): LDS broadcast + coalesced W0.
__global__ __launch_bounds__(1024, 2) void k1_grads(
    const float* __restrict__ y, const float* __restrict__ ws,
    const float* __restrict__ W0E, const float* __restrict__ b0E,
    const float* __restrict__ W1E, const float* __restrict__ b1E,
    const float* __restrict__ w2E,
    const float* __restrict__ W0S, const float* __restrict__ b0S,
    const float* __restrict__ W1S, const float* __restrict__ b1S,
    const float* __restrict__ w2S,
    float* __restrict__ odE, float* __restrict__ odS)
{
    __shared__ float syT[1024];       // [64][16]
    __shared__ float sH1T[4096];      // [256][16]
    __shared__ float sGT[4096];       // [256][16]  (G2)
    __shared__ float sG1T[4096];      // [256][16]  (G1)

    const int tid = threadIdx.x;
    const int sbase = blockIdx.x * SB;
    {
        int s = tid >> 6, i = tid & 63;
        syT[i * 16 + s] = y[sbase * 64 + tid];
    }
    __syncthreads();

    const int c = tid & 255, sg = tid >> 8, s4 = sg * 4;

    for (int m = 0; m < 2; ++m) {
        const float* w0t = ws + OFF_W0T + m * 16384;
        const float* w1t = ws + OFF_W1T + m * 65536;
        const float* W0 = m ? W0S : W0E;     // natural (256,64)
        const float* W1 = m ? W1S : W1E;     // natural (256,256)
        const float* b0 = m ? b0S : b0E;
        const float* b1 = m ? b1S : b1E;
        const float* w2 = m ? w2S : w2E;
        float* outg = m ? odS : odE;

        // L0: H1 = tanh(y @ W0^T + b0)
        {
            float4 acc = {0, 0, 0, 0};
            #pragma unroll 4
            for (int k = 0; k < 64; ++k)
                acc = f4fma(w0t[k * 256 + c], *(const float4*)(syT + k * 16 + s4), acc);
            *(float4*)(sH1T + c * 16 + s4) = tanh4b(acc, b0[c]);
        }
        __syncthreads();
        // L1: H2 = tanh(H1 @ W1^T + b1); fused G2 = (1-H2^2)*w2
        {
            float4 acc = {0, 0, 0, 0};
            #pragma unroll 4
            for (int k = 0; k < 256; ++k)
                acc = f4fma(w1t[k * 256 + c], *(const float4*)(sH1T + k * 16 + s4), acc);
            float b = b1[c], wv = w2[c];
            float4 h2 = make_float4(tanhf(acc.x + b), tanhf(acc.y + b),
                                    tanhf(acc.z + b), tanhf(acc.w + b));
            *(float4*)(sGT + c * 16 + s4) = make_float4(
                (1.f - h2.x * h2.x) * wv, (1.f - h2.y * h2.y) * wv,
                (1.f - h2.z * h2.z) * wv, (1.f - h2.w * h2.w) * wv);
        }
        __syncthreads();
        // U[k] = sum_j G2[j] * W1[j][k]; fused G1 = (1-H1^2)*U
        {
            float4 acc = {0, 0, 0, 0};
            #pragma unroll 4
            for (int j = 0; j < 256; ++j)
                acc = f4fma(W1[j * 256 + c], *(const float4*)(sGT + j * 16 + s4), acc);
            float4 h1 = *(const float4*)(sH1T + c * 16 + s4);
            *(float4*)(sG1T + c * 16 + s4) = make_float4(
                (1.f - h1.x * h1.x) * acc.x, (1.f - h1.y * h1.y) * acc.y,
                (1.f - h1.z * h1.z) * acc.z, (1.f - h1.w * h1.w) * acc.w);
        }
        __syncthreads();
        // dy[i] = sum_k G1[k] * W0[k][i]   (wave-uniform s -> LDS broadcast; W0 coalesced)
        {
            int s = tid >> 6, i = tid & 63;
            float acc = 0.f;
            #pragma unroll 8
            for (int k = 0; k < 256; ++k)
                acc = fmaf(sG1T[k * 16 + s], W0[k * 64 + i], acc);
            outg[sbase * 64 + tid] = acc;
        }
        __syncthreads();
    }
}

// ---------------- K2: pA head + poisson (atomic-free, weight-dedup), writes d_out ----------------
__global__ __launch_bounds__(1024, 4) void k2_poisson(
    const float* __restrict__ y, const float* __restrict__ ws,
    const float* __restrict__ b0P, const float* __restrict__ b1P,
    float* __restrict__ dout)
{
    extern __shared__ float smem[];
    float* sa   = smem;            // 16 x 2024 (a-values). Aliased: H1T @ [0,4096), yT @ [4096,5120)
    float* sH2T = smem + 32384;    // [256][16]
    float* sdE  = sH2T + 4096;     // [s][i]
    float* sdS  = sdE + 1024;
    // total 38528 floats = 154112 B

    float* sH1T = sa;              // alias [256][16] (dead before a-GEMM writes)
    float* syT  = sa + 4096;       // alias [64][16]  (dead after H1)

    const int tid = threadIdx.x;
    const int sbase = blockIdx.x * SB;
    const float* gdE = ws + OFF_DE;
    const float* gdS = ws + OFF_DS;

    // P0: one element per thread; y stored transposed
    {
        int s = tid >> 6, i = tid & 63;
        syT[i * 16 + s] = y[sbase * 64 + tid];
        sdE[tid] = gdE[sbase * 64 + tid];
        sdS[tid] = gdS[sbase * 64 + tid];
    }
    __syncthreads();

    const int c  = tid & 255;
    const int sg = tid >> 8;
    const int s4 = sg * 4;

    // P1: H1 = tanh(y @ W0^T + b0)
    {
        const float* w0t = ws + OFF_W0T + 2 * 16384;
        float4 acc = {0, 0, 0, 0};
        #pragma unroll 4
        for (int k = 0; k < 64; ++k) {
            float w = w0t[k * 256 + c];
            float4 yv = *(const float4*)(syT + k * 16 + s4);
            acc = f4fma(w, yv, acc);
        }
        *(float4*)(sH1T + c * 16 + s4) = tanh4b(acc, b0P[c]);
    }
    __syncthreads();

    // P2: H2 = tanh(H1 @ W1^T + b1)
    {
        const float* w1t = ws + OFF_W1T + 2 * 65536;
        float4 acc = {0, 0, 0, 0};
        #pragma unroll 4
        for (int k = 0; k < 256; ++k) {
            float w = w1t[k * 256 + c];
            float4 hv = *(const float4*)(sH1T + k * 16 + s4);
            acc = f4fma(w, hv, acc);
        }
        *(float4*)(sH2T + c * 16 + s4) = tanh4b(acc, b1P[c]);
    }
    __syncthreads();   // H1T/yT regions dead; sa fully writable

    // P3: a-GEMM, tiled 4 cols x 8 samples. cq<504 covers all 2016 cols.
    {
        const int sg2 = tid >> 9;           // 0..1 (sample octet)
        const int s8  = sg2 * 8;
        const int cq  = tid & 511;          // col quad
        if (cq < 504) {
            const float* wp = ws + OFF_W2PT + 4 * cq;
            float4 acc[8];
            #pragma unroll
            for (int s = 0; s < 8; ++s) acc[s] = make_float4(0.f, 0.f, 0.f, 0.f);
            #pragma unroll 2
            for (int k = 0; k < 256; ++k) {
                float4 hA = *(const float4*)(sH2T + k * 16 + s8);
                float4 hB = *(const float4*)(sH2T + k * 16 + s8 + 4);
                float4 w = *(const float4*)(wp + k * 2016);
                acc[0] = f4fma(hA.x, w, acc[0]);
                acc[1] = f4fma(hA.y, w, acc[1]);
                acc[2] = f4fma(hA.z, w, acc[2]);
                acc[3] = f4fma(hA.w, w, acc[3]);
                acc[4] = f4fma(hB.x, w, acc[4]);
                acc[5] = f4fma(hB.y, w, acc[5]);
                acc[6] = f4fma(hB.z, w, acc[6]);
                acc[7] = f4fma(hB.w, w, acc[7]);
            }
            #pragma unroll
            for (int s = 0; s < 8; ++s)
                *(float4*)(sa + (s8 + s) * 2024 + 4 * cq) = acc[s];
        }
    }
    __syncthreads();

    // P4: gather. thread -> sample s = tid>>6, row i = tid&63 (one wave per sample).
    {
        const int s = tid >> 6;
        const int i = tid & 63;
        const int ib = i * (i - 1) / 2;
        const float* ap = sa + s * 2024;
        const float* dep = sdE + s * 64;
        const float* dsp = sdS + s * 64;

        float adE = 0.f, adS = 0.f;
        int trij = 0;   // j*(j-1)/2
        #pragma unroll 4
        for (int j = 0; j < 64; ++j) {
            int t = (j < i) ? (ib + j) : (trij + i);
            float sel = (j < i) ? 1.f : ((j == i) ? 0.f : -1.f);
            float cc = sel * ap[t];
            adE = fmaf(cc, dep[j], adE);
            adS = fmaf(cc, dsp[j], adS);
            trij += j;
        }

        float de = dep[i], dsv = dsp[i];
        float p0 = de * adS;     // dE . AdS
        float p1 = de * dsv;     // dE . dS
        float p2 = dsv * dsv;    // dS . dS
        #pragma unroll
        for (int m = 1; m <= 32; m <<= 1) {
            p0 += __shfl_xor(p0, m);
            p1 += __shfl_xor(p1, m);
            p2 += __shfl_xor(p2, m);
        }
        float inv = 1.f / p2;
        dout[sbase * 64 + tid] = adE + (p0 * dsv - p1 * adS) * inv;
    }
}

// ---------------- K3: fC/fB heads + friction, accumulates into d_out ----------------
// 1024 threads, SB=16. R7 structure (merged forwards, 4x4 C-head, bm[16] Bm)
// + explicit software pipelining (prefetch w[k+1]/h[k+1]) in C-head and Bm loops.
__global__ __launch_bounds__(1024, 4) void k3_friction(
    const float* __restrict__ y, const float* __restrict__ ws,
    const float* __restrict__ b0C, const float* __restrict__ b1C,
    const float* __restrict__ b0B, const float* __restrict__ b1B,
    float* __restrict__ dout)
{
    extern __shared__ float smem[];
    float* sYT  = smem;               // [64][16]  y transposed
    float* sBTc = smem + 1024;        // [256][16] fC H2
    float* sBTb = smem + 5120;        // [256][16] fB H2
    float* sATc = smem + 9216;        // [256][16] fC H1 (dead after L1)
    float* sATb = smem + 13312;       // [256][16] fB H1 (dead after L1)
    float* sC   = smem + 9216;        // [16][1089] OVERLAPS sATc/sATb (written in C-head)
    float* sdE  = smem + 26640;       // [s][i]
    float* sdS  = sdE + 1024;
    float* sBdE = sdS + 1024;
    float* sBdS = sBdE + 1024;
    float* sv   = sBdS + 1024;
    float* sq   = sv + 1024;
    float* sScal = sq + 1024;         // 16*4
    float* sr   = sScal + 64;         // 16*16
    // total = 33104 floats = 132416 B

    const int tid = threadIdx.x;
    const int sbase = blockIdx.x * SB;
    const float* gdE = ws + OFF_DE;
    const float* gdS = ws + OFF_DS;

    {
        int s = tid >> 6, i = tid & 63;
        sYT[i * 16 + s] = y[sbase * 64 + tid];
        sdE[tid] = gdE[sbase * 64 + tid];
        sdS[tid] = gdS[sbase * 64 + tid];
    }
    if (tid < 64) sScal[tid] = 0.f;
    __syncthreads();

    {
        int s = tid >> 6;
        float de = sdE[tid];
        unsafeAtomicAdd(&sScal[s * 4 + 0], de * de);
        unsafeAtomicAdd(&sScal[s * 4 + 1], de * sdS[tid]);
    }

    // ---- merged forward mapping: net (0=fC,1=fB) x sample-quad x col-pair ----
    const int net = tid >> 9;
    const int t9  = tid & 511;
    const int sgf = t9 >> 7;          // 0..3
    const int s4f = sgf * 4;
    const int cp  = t9 & 127;         // col pair
    const int c0 = 2 * cp, c1 = c0 + 1;
    const float* w0t = ws + OFF_W0T + (3 + net) * 16384;
    const float* w1t = ws + OFF_W1T + (3 + net) * 65536;
    const float* b0v = net ? b0B : b0C;
    const float* b1v = net ? b1B : b1C;
    float* sH1 = net ? sATb : sATc;
    float* sH2 = net ? sBTb : sBTc;

    // ============ L0 (both nets): H1 = tanh(y @ W0^T + b0) ============
    {
        float4 a0 = {0, 0, 0, 0}, a1 = {0, 0, 0, 0};
        #pragma unroll 4
        for (int k = 0; k < 64; ++k) {
            float4 h = *(const float4*)(sYT + k * 16 + s4f);
            float2 w = *(const float2*)(w0t + k * 256 + c0);
            a0 = f4fma(w.x, h, a0);
            a1 = f4fma(w.y, h, a1);
        }
        *(float4*)(sH1 + c0 * 16 + s4f) = tanh4b(a0, b0v[c0]);
        *(float4*)(sH1 + c1 * 16 + s4f) = tanh4b(a1, b0v[c1]);
    }
    __syncthreads();

    // ============ L1 (both nets): H2 = tanh(H1 @ W1^T + b1) ============
    {
        float4 a0 = {0, 0, 0, 0}, a1 = {0, 0, 0, 0};
        #pragma unroll 4
        for (int k = 0; k < 256; ++k) {
            float4 h = *(const float4*)(sH1 + k * 16 + s4f);
            float2 w = *(const float2*)(w1t + k * 256 + c0);
            a0 = f4fma(w.x, h, a0);
            a1 = f4fma(w.y, h, a1);
        }
        *(float4*)(sH2 + c0 * 16 + s4f) = tanh4b(a0, b1v[c0]);
        *(float4*)(sH2 + c1 * 16 + s4f) = tanh4b(a1, b1v[c1]);
    }
    __syncthreads();   // H1 tiles dead from here; sC region writable

    // ============ C head: thread = 4 cols x 4 samples, software-pipelined ============
    {
        const int sgc = tid >> 8;         // 0..3
        const int s4c = sgc * 4;
        const int cq  = tid & 255;        // col quad: cols 4cq..4cq+3
        const float* w2ct = ws + OFF_W2CT + 4 * cq;
        float4 a0 = {0,0,0,0}, a1 = {0,0,0,0}, a2 = {0,0,0,0}, a3 = {0,0,0,0};
        float4 h = *(const float4*)(sBTc + s4c);
        float4 w = *(const float4*)(w2ct);
        #pragma unroll 2
        for (int k = 0; k < 256; ++k) {
            // prefetch k+1 (one-past-end reads land in adjacent allocated regions)
            float4 hn = *(const float4*)(sBTc + (k + 1) * 16 + s4c);
            float4 wn = *(const float4*)(w2ct + (k + 1) * 1024);
            a0 = f4fma(h.x, w, a0);
            a1 = f4fma(h.y, w, a1);
            a2 = f4fma(h.z, w, a2);
            a3 = f4fma(h.w, w, a3);
            h = hn; w = wn;
        }
        const int kC = cq >> 2;            // C row (DD index of this col group)
        const int mB = 4 * (cq & 3);       // C col base
        float* p0 = sC + (s4c + 0) * 1089 + kC * 17 + mB;
        float* p1 = sC + (s4c + 1) * 1089 + kC * 17 + mB;
        float* p2 = sC + (s4c + 2) * 1089 + kC * 17 + mB;
        float* p3 = sC + (s4c + 3) * 1089 + kC * 17 + mB;
        p0[0] = a0.x; p0[1] = a0.y; p0[2] = a0.z; p0[3] = a0.w;
        p1[0] = a1.x; p1[1] = a1.y; p1[2] = a1.z; p1[3] = a1.w;
        p2[0] = a2.x; p2[1] = a2.y; p2[2] = a2.z; p2[3] = a2.w;
        p3[0] = a3.x; p3[1] = a3.y; p3[2] = a3.z; p3[3] = a3.w;
    }
    __syncthreads();

    // ============ Bm pass1: bm[16] float4 held for pass2, software-pipelined ============
    const int kp = tid >> 4;          // Bm row 0..63
    const int i0 = 4 * (tid & 15);    // Bm col segment
    float4 bm[16];
    #pragma unroll
    for (int s = 0; s < 16; ++s) bm[s] = make_float4(0.f, 0.f, 0.f, 0.f);
    {
        const float* wb = ws + OFF_W2BT + 4 * tid;
        float4 w = *(const float4*)(wb);
        float4 h0 = *(const float4*)(sBTb);
        float4 h1 = *(const float4*)(sBTb + 4);
        float4 h2 = *(const float4*)(sBTb + 8);
        float4 h3 = *(const float4*)(sBTb + 12);
        #pragma unroll 2
        for (int k = 0; k < 256; ++k) {
            // prefetch k+1 (one-past-end reads land in adjacent allocated regions)
            float4 wn = *(const float4*)(wb + (k + 1) * 4096);
            float4 g0 = *(const float4*)(sBTb + (k + 1) * 16);
            float4 g1 = *(const float4*)(sBTb + (k + 1) * 16 + 4);
            float4 g2 = *(const float4*)(sBTb + (k + 1) * 16 + 8);
            float4 g3 = *(const float4*)(sBTb + (k + 1) * 16 + 12);
            float hs[16] = {h0.x, h0.y, h0.z, h0.w, h1.x, h1.y, h1.z, h1.w,
                            h2.x, h2.y, h2.z, h2.w, h3.x, h3.y, h3.z, h3.w};
            #pragma unroll
            for (int s = 0; s < 16; ++s) bm[s] = f4fma(hs[s], w, bm[s]);
            w = wn; h0 = g0; h1 = g1; h2 = g2; h3 = g3;
        }
    }
    // BdotdE/BdotdS: reduce over i via 16-lane shfl
    #pragma unroll
    for (int s = 0; s < 16; ++s) {
        float4 de = *(const float4*)(sdE + s * 64 + i0);
        float4 dsv = *(const float4*)(sdS + s * 64 + i0);
        float pd = dot4f(bm[s], de);
        float ps = dot4f(bm[s], dsv);
        pd += __shfl_xor(pd, 1); ps += __shfl_xor(ps, 1);
        pd += __shfl_xor(pd, 2); ps += __shfl_xor(ps, 2);
        pd += __shfl_xor(pd, 4); ps += __shfl_xor(ps, 4);
        pd += __shfl_xor(pd, 8); ps += __shfl_xor(ps, 8);
        if ((tid & 15) == 0) {
            sBdE[s * 64 + kp] = pd;
            sBdS[s * 64 + kp] = ps;
        }
    }
    __syncthreads();

    // v = BdS - beta*BdE  (one element per thread)
    {
        int s = tid >> 6;
        float beta = sScal[s * 4 + 1] / sScal[s * 4 + 0];
        sv[tid] = sBdS[tid] - beta * sBdE[tid];
    }
    __syncthreads();
    {
        int s = tid >> 6;
        unsafeAtomicAdd(&sScal[s * 4 + 2], sdE[tid] * sv[tid]);
    }
    __syncthreads();

    // ============ pass2: q = Bm @ v from registers ============
    #pragma unroll
    for (int s = 0; s < 16; ++s) {
        float4 vv = *(const float4*)(sv + s * 64 + i0);
        float pq = dot4f(bm[s], vv);
        pq += __shfl_xor(pq, 1);
        pq += __shfl_xor(pq, 2);
        pq += __shfl_xor(pq, 4);
        pq += __shfl_xor(pq, 8);
        if ((tid & 15) == 0) sq[s * 64 + kp] = pq;
    }
    __syncthreads();

    // r[m] = sum_k C[k,m] * (q[k] - gamma*BdE[k])
    if (tid < 256) {
        int s = tid >> 4, m = tid & 15;
        float gamma = sScal[s * 4 + 2] / sScal[s * 4 + 0];
        float r = 0.f;
        #pragma unroll 4
        for (int k = 0; k < 64; ++k) {
            float wv = sq[s * 64 + k] - gamma * sBdE[s * 64 + k];
            r = fmaf(sC[s * 1089 + k * 17 + m], wv, r);
        }
        sr[s * 16 + m] = r;
    }
    __syncthreads();
    // out_k += sum_m C[k,m] * r[m]  (one element per thread)
    {
        int s = tid >> 6, k = tid & 63;
        float o = 0.f;
        #pragma unroll
        for (int m2 = 0; m2 < 16; ++m2)
            o = fmaf(sC[s * 1089 + k * 17 + m2], sr[s * 16 + m2], o);
        int gi = sbase * 64 + tid;
        dout[gi] = dout[gi] + o;
    }
}

extern "C" void kernel_launch(void* const* d_in, const int* in_sizes, int n_in,
                              void* d_out, int out_size, void* d_ws, size_t ws_size,
                              hipStream_t stream)
{
    (void)in_sizes; (void)n_in; (void)out_size;
    const float* y = (const float*)d_in[1];
    const float* W0[5]; const float* b0[5]; const float* W1[5]; const float* b1[5]; const float* W2[5];
    for (int m = 0; m < 5; ++m) {
        int base = 2 + m * 5;
        W0[m] = (const float*)d_in[base + 0];
        b0[m] = (const float*)d_in[base + 1];
        W1[m] = (const float*)d_in[base + 2];
        b1[m] = (const float*)d_in[base + 3];
        W2[m] = (const float*)d_in[base + 4];
    }
    float* ws = (float*)d_ws;
    float* dout = (float*)d_out;
    if (ws_size < (size_t)WS_FLOATS * sizeof(float)) return;

    for (int m = 0; m < 5; ++m) {
        hipLaunchKernelGGL(k_transpose, dim3((256 * 64 + 255) / 256), dim3(256), 0, stream,
                           W0[m], ws + OFF_W0T + m * 16384, 256, 64);
        hipLaunchKernelGGL(k_transpose, dim3((256 * 256 + 255) / 256), dim3(256), 0, stream,
                           W1[m], ws + OFF_W1T + m * 65536, 256, 256);
    }
    hipLaunchKernelGGL(k_transpose, dim3((2016 * 256 + 255) / 256), dim3(256), 0, stream,
                       W2[2], ws + OFF_W2PT, 2016, 256);
    hipLaunchKernelGGL(k_transpose, dim3((1024 * 256 + 255) / 256), dim3(256), 0, stream,
                       W2[3], ws + OFF_W2CT, 1024, 256);
    hipLaunchKernelGGL(k_transpose, dim3((4096 * 256 + 255) / 256), dim3(256), 0, stream,
                       W2[4], ws + OFF_W2BT, 4096, 256);

    hipLaunchKernelGGL(k1_grads, dim3(1024), dim3(1024), 0, stream,
                       y, ws,
                       W0[0], b0[0], W1[0], b1[0], W2[0],
                       W0[1], b0[1], W1[1], b1[1], W2[1],
                       ws + OFF_DE, ws + OFF_DS);

    const int k2_smem = 154112;
    hipFuncSetAttribute((const void*)k2_poisson, hipFuncAttributeMaxDynamicSharedMemorySize, k2_smem);
    hipLaunchKernelGGL(k2_poisson, dim3(1024), dim3(1024), k2_smem, stream,
                       y, ws, b0[2], b1[2], dout);

    const int k3_smem = 132416;
    hipFuncSetAttribute((const void*)k3_friction, hipFuncAttributeMaxDynamicSharedMemorySize, k3_smem);
    hipLaunchKernelGGL(k3_friction, dim3(1024), dim3(1024), k3_smem, stream,
                       y, ws, b0[3], b1[3], b0[4], b1[4], dout);
}